// Round 1
// baseline (1430.123 us; speedup 1.0000x reference)
//
#include <hip/hip_runtime.h>
#include <hip/hip_bf16.h>
#include <math.h>

// Problem constants
#define NB 2
#define NN 512
#define DCS 512
#define DCZ 128
#define NH 8
#define DC 16
#define NPQ 8
#define NPV 12

static constexpr float W_L  = 0.14433756729740643f;  // sqrt(1/(3*16))
static constexpr float W_C  = 0.09622504486493764f;  // sqrt(1/(3*36))
static constexpr float S13  = 0.57735026918962576f;  // sqrt(1/3)
static constexpr float F_INF = 100000.0f;
static constexpr float F_EPS = 1e-8f;

// workspace float offsets
static constexpr size_t OFF_Q  = 0;          // 2*512*128 = 131072
static constexpr size_t OFF_K  = 131072;
static constexpr size_t OFF_V  = 262144;
static constexpr size_t OFF_QP = 393216;     // 2*512*192
static constexpr size_t OFF_KP = 589824;
static constexpr size_t OFF_VP = 786432;     // 2*512*288
static constexpr size_t OFF_BT = 1081344;    // 2*8*512*512 = 4194304
static constexpr size_t OFF_FT = 5275648;    // 2*512*1536 = 1572864
// total = 6848512 floats = 27.4 MB

// ---------------------------------------------------------------------------
// Kernel 1: all projections from seqs. One block per (b,i) row.
// q:(row,h*16+c)  k/v:(row,h*16+c)  q_pts/k_pts:(row,(h*8+p)*3+x)
// v_pts:(row,(h*12+p)*3+x).  Points get +t folded in.
// ---------------------------------------------------------------------------
__global__ __launch_bounds__(256) void k_proj(
    const float* __restrict__ seqs, const float* __restrict__ x_t, const float* __restrict__ mask,
    const float* __restrict__ Wq,  const float* __restrict__ bq,
    const float* __restrict__ Wkv, const float* __restrict__ bkv,
    const float* __restrict__ Wqp, const float* __restrict__ bqp,
    const float* __restrict__ Wkvp,const float* __restrict__ bkvp,
    float* __restrict__ ws)
{
  const int row = blockIdx.x;
  __shared__ float s[DCS];
  __shared__ float t[3];
  for (int k0 = threadIdx.x; k0 < DCS; k0 += 256)
    s[k0] = seqs[(size_t)row * DCS + k0];
  if (threadIdx.x < 3)
    t[threadIdx.x] = x_t[row*3 + threadIdx.x] * mask[row];
  __syncthreads();

  float* q  = ws + OFF_Q;
  float* kk = ws + OFF_K;
  float* v  = ws + OFF_V;
  float* qp = ws + OFF_QP;
  float* kp = ws + OFF_KP;
  float* vp = ws + OFF_VP;

  for (int col = threadIdx.x; col < 1056; col += 256) {
    const float* W; const float* bb_; int c, ncol;
    if (col < 128)      { W = Wq;   bb_ = bq;   c = col;       ncol = 128; }
    else if (col < 384) { W = Wkv;  bb_ = bkv;  c = col - 128; ncol = 256; }
    else if (col < 576) { W = Wqp;  bb_ = bqp;  c = col - 384; ncol = 192; }
    else                { W = Wkvp; bb_ = bkvp; c = col - 576; ncol = 480; }
    float acc = 0.f;
    #pragma unroll 4
    for (int k0 = 0; k0 < DCS; ++k0)
      acc = fmaf(s[k0], W[(size_t)k0 * ncol + c], acc);
    acc += bb_[c];
    if (col < 128) {
      q[(size_t)row*128 + c] = acc;
    } else if (col < 384) {
      int h = c >> 5, r = c & 31;
      if (r < 16) kk[(size_t)row*128 + h*16 + r] = acc;
      else        v [(size_t)row*128 + h*16 + (r-16)] = acc;
    } else if (col < 576) {
      int x = c / 64, rem = c % 64, h = rem >> 3, p = rem & 7;
      qp[(size_t)row*192 + (h*8+p)*3 + x] = acc + t[x];
    } else {
      int x = c / 160, rem = c % 160, h = rem / 20, p = rem % 20;
      float val = acc + t[x];
      if (p < 8) kp[(size_t)row*192 + (h*8+p)*3 + x] = val;
      else       vp[(size_t)row*288 + (h*12 + (p-8))*3 + x] = val;
    }
  }
}

// ---------------------------------------------------------------------------
// Kernel 2: biasT[b,h,i,j] = sqrt(1/3) * (pair_rep[b,i,j,:] @ Wb[:,h] + bb[h])
// One wave per pair row; lane z covers z and z+64; shuffle reduce.
// ---------------------------------------------------------------------------
__global__ __launch_bounds__(256) void k_bias(
    const float* __restrict__ pair, const float* __restrict__ Wb, const float* __restrict__ bb,
    float* __restrict__ biasT)
{
  __shared__ float sW[NH * DCZ];  // [h][z] transposed
  const int tid = threadIdx.x;
  for (int idx = tid; idx < NH*DCZ; idx += 256) {
    int h = idx >> 7, z = idx & 127;
    sW[idx] = Wb[z*NH + h];
  }
  __syncthreads();
  const size_t rowbase = (size_t)blockIdx.x * 4 + (tid >> 6);
  const int lane = tid & 63;
  const float* pr = pair + rowbase * DCZ;
  float p0 = pr[lane], p1 = pr[lane + 64];
  float partial[NH];
  #pragma unroll
  for (int h = 0; h < NH; ++h)
    partial[h] = fmaf(p0, sW[h*DCZ + lane], p1 * sW[h*DCZ + 64 + lane]);
  #pragma unroll
  for (int off = 32; off; off >>= 1) {
    #pragma unroll
    for (int h = 0; h < NH; ++h)
      partial[h] += __shfl_xor(partial[h], off, 64);
  }
  if (lane < NH) {
    size_t r = rowbase;
    int j = (int)(r % NN); r /= NN;
    int i = (int)(r % NN);
    int b = (int)(r / NN);
    biasT[((size_t)(b*NH + lane) * NN + i) * NN + j] = S13 * (partial[lane] + bb[lane]);
  }
}

// ---------------------------------------------------------------------------
// Kernel 3: attention, one block per (b,i), 512 threads, all 8 heads fused
// so pair_rep row is read once.
// ---------------------------------------------------------------------------
__global__ __launch_bounds__(512) void k_attn(
    const float* __restrict__ pair, const float* __restrict__ x_t, const float* __restrict__ mask,
    const float* __restrict__ head_w, float* __restrict__ ws)
{
  const int row = blockIdx.x;
  const int b = row >> 9, i = row & 511;
  const int tid = threadIdx.x;

  const float* q  = ws + OFF_Q;
  const float* kk = ws + OFF_K;
  const float* v  = ws + OFF_V;
  const float* qp = ws + OFF_QP;
  const float* kp = ws + OFF_KP;
  const float* vp = ws + OFF_VP;
  const float* bt = ws + OFF_BT;
  float* feats = ws + OFF_FT;

  __shared__ float sA[NH][NN];     // 16 KB
  __shared__ float sQ[128];
  __shared__ float sQP[192];
  __shared__ float sOPT[288];
  __shared__ float sHW[NH];
  __shared__ float sT[3];
  __shared__ float sMi;

  if (tid < 128) sQ[tid] = q[(size_t)row*128 + tid];
  else if (tid < 320) sQP[tid-128] = qp[(size_t)row*192 + (tid-128)];
  else if (tid < 328) {
    float x = head_w[tid-320];
    float sp = (x > 20.f) ? x : log1pf(expf(x));
    sHW[tid-320] = 0.5f * W_C * sp;
  }
  else if (tid == 328) sMi = mask[row];
  else if (tid >= 336 && tid < 339) sT[tid-336] = x_t[row*3 + (tid-336)] * mask[row];
  __syncthreads();

  // ---- logits: thread j computes all 8 heads ----
  {
    const int j = tid;
    const float mj = mask[b*NN + j];
    const float mterm = F_INF * (sMi * mj - 1.0f);
    const float* kr  = kk + (size_t)(b*NN + j) * 128;
    const float* kpr = kp + (size_t)(b*NN + j) * 192;
    #pragma unroll
    for (int h = 0; h < NH; ++h) {
      float dot = 0.f;
      const float4* k4 = (const float4*)(kr + h*16);
      const float4* q4 = (const float4*)(sQ + h*16);
      #pragma unroll
      for (int u = 0; u < 4; ++u) {
        float4 a = q4[u], c = k4[u];
        dot += a.x*c.x + a.y*c.y + a.z*c.z + a.w*c.w;
      }
      float d2 = 0.f;
      const float4* qp4 = (const float4*)(sQP + h*24);
      const float4* kp4 = (const float4*)(kpr + h*24);
      #pragma unroll
      for (int u = 0; u < 6; ++u) {
        float4 a = qp4[u], c = kp4[u];
        float dx = a.x-c.x, dy = a.y-c.y, dz = a.z-c.z, dw = a.w-c.w;
        d2 += dx*dx + dy*dy + dz*dz + dw*dw;
      }
      float logit = W_L * dot + bt[((size_t)(b*NH + h)*NN + i)*NN + j] - sHW[h]*d2 + mterm;
      sA[h][j] = logit;
    }
  }
  __syncthreads();

  // ---- softmax: wave w handles head w ----
  {
    const int h = tid >> 6, lane = tid & 63;
    float vals[8]; float m = -3.0e38f;
    #pragma unroll
    for (int r = 0; r < 8; ++r) { vals[r] = sA[h][lane + 64*r]; m = fmaxf(m, vals[r]); }
    #pragma unroll
    for (int off = 32; off; off >>= 1) m = fmaxf(m, __shfl_xor(m, off, 64));
    float ssum = 0.f;
    #pragma unroll
    for (int r = 0; r < 8; ++r) { vals[r] = __expf(vals[r] - m); ssum += vals[r]; }
    #pragma unroll
    for (int off = 32; off; off >>= 1) ssum += __shfl_xor(ssum, off, 64);
    const float inv = 1.0f / ssum;
    #pragma unroll
    for (int r = 0; r < 8; ++r) sA[h][lane + 64*r] = vals[r] * inv;
  }
  __syncthreads();

  // ---- o (threads 0..127) and o_pt (threads 128..415) ----
  if (tid < 128) {
    const int h = tid >> 4;
    float acc = 0.f;
    #pragma unroll 4
    for (int j = 0; j < NN; ++j)
      acc = fmaf(sA[h][j], v[(size_t)(b*NN + j)*128 + tid], acc);
    feats[(size_t)row*1536 + tid] = acc;
  } else if (tid < 416) {
    const int idx = tid - 128;             // h*36 + p*3 + x
    const int h = idx / 36, r2 = idx % 36, p = r2 / 3, x = r2 % 3;
    float acc = 0.f;
    #pragma unroll 4
    for (int j = 0; j < NN; ++j)
      acc = fmaf(sA[h][j], vp[(size_t)(b*NN + j)*288 + idx], acc);
    acc -= sT[x];
    sOPT[idx] = acc;
    feats[(size_t)row*1536 + 128 + x*96 + h*12 + p] = acc;
  }
  __syncthreads();

  // ---- o_pt norms ----
  if (tid < 96) {
    float xx = sOPT[tid*3], yy = sOPT[tid*3+1], zz = sOPT[tid*3+2];
    feats[(size_t)row*1536 + 416 + tid] = sqrtf(xx*xx + yy*yy + zz*zz + F_EPS);
  }

  // ---- o_pair: wave w = head w, lane covers 2 z via float2 ----
  {
    const int h = tid >> 6, z2 = tid & 63;
    const float2* pr = (const float2*)(pair + ((size_t)(b*NN + i)) * NN * DCZ);
    float ax = 0.f, ay = 0.f;
    #pragma unroll 4
    for (int j = 0; j < NN; ++j) {
      float a = sA[h][j];
      float2 p = pr[(size_t)j*64 + z2];
      ax = fmaf(a, p.x, ax); ay = fmaf(a, p.y, ay);
    }
    feats[(size_t)row*1536 + 512 + h*128 + 2*z2]     = ax;
    feats[(size_t)row*1536 + 512 + h*128 + 2*z2 + 1] = ay;
  }
}

// ---------------------------------------------------------------------------
// Kernel 4: out = (seqs + feats @ Wout + bout) * mask
// 8 rows per block, 2 col-halves, 256 threads.
// ---------------------------------------------------------------------------
__global__ __launch_bounds__(256) void k_out(
    const float* __restrict__ Wout, const float* __restrict__ bout,
    const float* __restrict__ seqs, const float* __restrict__ mask,
    const float* __restrict__ ws, float* __restrict__ out)
{
  const int rg = blockIdx.x >> 1;
  const int ch = blockIdx.x & 1;
  const int tid = threadIdx.x;
  const int c = ch*256 + tid;
  const float* feats = ws + OFF_FT;

  __shared__ float s[8][1536];   // 48 KB
  for (int idx = tid; idx < 8*1536; idx += 256) {
    int r = idx / 1536, k0 = idx % 1536;
    s[r][k0] = feats[(size_t)(rg*8 + r)*1536 + k0];
  }
  __syncthreads();

  float acc[8];
  #pragma unroll
  for (int r = 0; r < 8; ++r) acc[r] = bout[c];
  for (int k0 = 0; k0 < 1536; k0 += 4) {
    float w0 = Wout[(size_t)(k0+0)*512 + c];
    float w1 = Wout[(size_t)(k0+1)*512 + c];
    float w2 = Wout[(size_t)(k0+2)*512 + c];
    float w3 = Wout[(size_t)(k0+3)*512 + c];
    #pragma unroll
    for (int r = 0; r < 8; ++r) {
      float4 sv = *(const float4*)&s[r][k0];
      acc[r] = fmaf(sv.x, w0, fmaf(sv.y, w1, fmaf(sv.z, w2, fmaf(sv.w, w3, acc[r]))));
    }
  }
  #pragma unroll
  for (int r = 0; r < 8; ++r) {
    size_t row = (size_t)rg*8 + r;
    out[row*512 + c] = (seqs[row*512 + c] + acc[r]) * mask[row];
  }
}

// ---------------------------------------------------------------------------
extern "C" void kernel_launch(void* const* d_in, const int* in_sizes, int n_in,
                              void* d_out, int out_size, void* d_ws, size_t ws_size,
                              hipStream_t stream)
{
  const float* seqs   = (const float*)d_in[0];
  const float* pair   = (const float*)d_in[1];
  const float* x_t    = (const float*)d_in[2];
  const float* mask   = (const float*)d_in[3];
  const float* Wq     = (const float*)d_in[4];
  const float* bq     = (const float*)d_in[5];
  const float* Wkv    = (const float*)d_in[6];
  const float* bkv    = (const float*)d_in[7];
  const float* Wqp    = (const float*)d_in[8];
  const float* bqp    = (const float*)d_in[9];
  const float* Wkvp   = (const float*)d_in[10];
  const float* bkvp   = (const float*)d_in[11];
  const float* Wb     = (const float*)d_in[12];
  const float* bb     = (const float*)d_in[13];
  const float* head_w = (const float*)d_in[14];
  const float* Wout   = (const float*)d_in[15];
  const float* bout   = (const float*)d_in[16];
  float* out = (float*)d_out;
  float* ws  = (float*)d_ws;

  hipLaunchKernelGGL(k_proj, dim3(NB*NN), dim3(256), 0, stream,
                     seqs, x_t, mask, Wq, bq, Wkv, bkv, Wqp, bqp, Wkvp, bkvp, ws);
  hipLaunchKernelGGL(k_bias, dim3(NB*NN*NN/4), dim3(256), 0, stream,
                     pair, Wb, bb, ws + OFF_BT);
  hipLaunchKernelGGL(k_attn, dim3(NB*NN), dim3(512), 0, stream,
                     pair, x_t, mask, head_w, ws);
  hipLaunchKernelGGL(k_out, dim3(NB*NN/8*2), dim3(256), 0, stream,
                     Wout, bout, seqs, mask, ws, out);
}

// Round 2
// 1026.610 us; speedup vs baseline: 1.3931x; 1.3931x over previous
//
#include <hip/hip_runtime.h>
#include <hip/hip_bf16.h>
#include <math.h>

// Problem constants
#define NB 2
#define NN 512
#define DCS 512
#define DCZ 128
#define NH 8
#define DC 16
#define NPQ 8
#define NPV 12

static constexpr float W_L  = 0.14433756729740643f;  // sqrt(1/(3*16))
static constexpr float W_C  = 0.09622504486493764f;  // sqrt(1/(3*36))
static constexpr float S13  = 0.57735026918962576f;  // sqrt(1/3)
static constexpr float F_INF = 100000.0f;
static constexpr float F_EPS = 1e-8f;

// workspace float offsets
static constexpr size_t OFF_Q  = 0;          // 2*512*128
static constexpr size_t OFF_K  = 131072;
static constexpr size_t OFF_V  = 262144;
static constexpr size_t OFF_QP = 393216;     // 2*512*192
static constexpr size_t OFF_KP = 589824;
static constexpr size_t OFF_VP = 786432;     // 2*512*288
static constexpr size_t OFF_FT = 1081344;    // 2*512*1536

// ---------------------------------------------------------------------------
// Kernel 1: all projections from seqs. 4 rows per block, 512 threads.
// q:(row,h*16+c)  k/v:(row,h*16+c)  q_pts/k_pts:(row,(h*8+p)*3+x)
// v_pts:(row,(h*12+p)*3+x).  Points get +t folded in.
// ---------------------------------------------------------------------------
__global__ __launch_bounds__(512) void k_proj(
    const float* __restrict__ seqs, const float* __restrict__ x_t, const float* __restrict__ mask,
    const float* __restrict__ Wq,  const float* __restrict__ bq,
    const float* __restrict__ Wkv, const float* __restrict__ bkv,
    const float* __restrict__ Wqp, const float* __restrict__ bqp,
    const float* __restrict__ Wkvp,const float* __restrict__ bkvp,
    float* __restrict__ ws)
{
  const int r0 = blockIdx.x * 4;
  __shared__ float s[4][DCS];     // 8 KB
  __shared__ float t[4][3];
  for (int idx = threadIdx.x; idx < 4*DCS; idx += 512) {
    int r = idx >> 9, k0 = idx & 511;
    s[r][k0] = seqs[(size_t)(r0 + r) * DCS + k0];
  }
  if (threadIdx.x < 12) {
    int r = threadIdx.x / 3, x = threadIdx.x % 3;
    t[r][x] = x_t[(r0 + r)*3 + x] * mask[r0 + r];
  }
  __syncthreads();

  float* q  = ws + OFF_Q;
  float* kk = ws + OFF_K;
  float* v  = ws + OFF_V;
  float* qp = ws + OFF_QP;
  float* kp = ws + OFF_KP;
  float* vp = ws + OFF_VP;

  for (int col = threadIdx.x; col < 1056; col += 512) {
    const float* W; const float* bb_; int c, ncol;
    if (col < 128)      { W = Wq;   bb_ = bq;   c = col;       ncol = 128; }
    else if (col < 384) { W = Wkv;  bb_ = bkv;  c = col - 128; ncol = 256; }
    else if (col < 576) { W = Wqp;  bb_ = bqp;  c = col - 384; ncol = 192; }
    else                { W = Wkvp; bb_ = bkvp; c = col - 576; ncol = 480; }
    float acc0 = bb_[c], acc1 = bb_[c], acc2 = bb_[c], acc3 = bb_[c];
    #pragma unroll 4
    for (int k0 = 0; k0 < DCS; ++k0) {
      float w = W[(size_t)k0 * ncol + c];
      acc0 = fmaf(s[0][k0], w, acc0);
      acc1 = fmaf(s[1][k0], w, acc1);
      acc2 = fmaf(s[2][k0], w, acc2);
      acc3 = fmaf(s[3][k0], w, acc3);
    }
    float accs[4] = {acc0, acc1, acc2, acc3};
    #pragma unroll
    for (int r = 0; r < 4; ++r) {
      const size_t row = (size_t)(r0 + r);
      const float acc = accs[r];
      if (col < 128) {
        q[row*128 + c] = acc;
      } else if (col < 384) {
        int h = c >> 5, rr = c & 31;
        if (rr < 16) kk[row*128 + h*16 + rr] = acc;
        else         v [row*128 + h*16 + (rr-16)] = acc;
      } else if (col < 576) {
        int x = c / 64, rem = c % 64, h = rem >> 3, p = rem & 7;
        qp[row*192 + (h*8+p)*3 + x] = acc + t[r][x];
      } else {
        int x = c / 160, rem = c % 160, h = rem / 20, p = rem % 20;
        float val = acc + t[r][x];
        if (p < 8) kp[row*192 + (h*8+p)*3 + x] = val;
        else       vp[row*288 + (h*12 + (p-8))*3 + x] = val;
      }
    }
  }
}

// ---------------------------------------------------------------------------
// Kernel 2: attention, one block per (b,i), 512 threads, all 8 heads fused.
// Bias (pair @ Wb) computed inline in the logit phase -> pair is read twice
// per block back-to-back (second read hits L3).
// ---------------------------------------------------------------------------
__global__ __launch_bounds__(512) void k_attn(
    const float* __restrict__ pair, const float* __restrict__ x_t, const float* __restrict__ mask,
    const float* __restrict__ head_w, const float* __restrict__ Wb, const float* __restrict__ bb,
    float* __restrict__ ws)
{
  const int row = blockIdx.x;
  const int b = row >> 9, i = row & 511;
  const int tid = threadIdx.x;

  const float* q  = ws + OFF_Q;
  const float* kk = ws + OFF_K;
  const float* v  = ws + OFF_V;
  const float* qp = ws + OFF_QP;
  const float* kp = ws + OFF_KP;
  const float* vp = ws + OFF_VP;
  float* feats = ws + OFF_FT;

  __shared__ float sA[NH][NN];     // 16 KB
  __shared__ float sWb[NH * DCZ]; // 4 KB, [h][z]
  __shared__ float sQ[128];
  __shared__ float sQP[192];
  __shared__ float sOPT[288];
  __shared__ float sHW[NH];
  __shared__ float sT[3];
  __shared__ float sMi;

  for (int idx = tid; idx < NH*DCZ; idx += 512) {
    int h = idx >> 7, z = idx & 127;
    sWb[idx] = Wb[z*NH + h];
  }
  if (tid < 128) sQ[tid] = q[(size_t)row*128 + tid];
  else if (tid < 320) sQP[tid-128] = qp[(size_t)row*192 + (tid-128)];
  else if (tid < 328) {
    float x = head_w[tid-320];
    float sp = (x > 20.f) ? x : log1pf(expf(x));
    sHW[tid-320] = 0.5f * W_C * sp;
  }
  else if (tid == 328) sMi = mask[row];
  else if (tid >= 336 && tid < 339) sT[tid-336] = x_t[row*3 + (tid-336)] * mask[row];
  __syncthreads();

  // ---- logits (incl. inline pair-bias): thread j computes all 8 heads ----
  {
    const int j = tid;
    const float mj = mask[b*NN + j];
    const float mterm = F_INF * (sMi * mj - 1.0f);

    // bias: dot(pair_row, Wb[:,h]) for all h
    float accb[NH];
    #pragma unroll
    for (int h = 0; h < NH; ++h) accb[h] = bb[h];
    const float4* prow4 = (const float4*)(pair + ((size_t)(b*NN + i)*NN + j) * DCZ);
    const float4* sWb4  = (const float4*)sWb;
    #pragma unroll 4
    for (int zc = 0; zc < 32; ++zc) {
      float4 pv = prow4[zc];
      #pragma unroll
      for (int h = 0; h < NH; ++h) {
        float4 w = sWb4[h*32 + zc];
        accb[h] = fmaf(pv.x, w.x, fmaf(pv.y, w.y, fmaf(pv.z, w.z, fmaf(pv.w, w.w, accb[h]))));
      }
    }

    const float* kr  = kk + (size_t)(b*NN + j) * 128;
    const float* kpr = kp + (size_t)(b*NN + j) * 192;
    #pragma unroll
    for (int h = 0; h < NH; ++h) {
      float dot = 0.f;
      const float4* k4 = (const float4*)(kr + h*16);
      const float4* q4 = (const float4*)(sQ + h*16);
      #pragma unroll
      for (int u = 0; u < 4; ++u) {
        float4 a = q4[u], c = k4[u];
        dot += a.x*c.x + a.y*c.y + a.z*c.z + a.w*c.w;
      }
      float d2 = 0.f;
      const float4* qp4 = (const float4*)(sQP + h*24);
      const float4* kp4 = (const float4*)(kpr + h*24);
      #pragma unroll
      for (int u = 0; u < 6; ++u) {
        float4 a = qp4[u], c = kp4[u];
        float dx = a.x-c.x, dy = a.y-c.y, dz = a.z-c.z, dw = a.w-c.w;
        d2 += dx*dx + dy*dy + dz*dz + dw*dw;
      }
      sA[h][j] = W_L * dot + S13 * accb[h] - sHW[h]*d2 + mterm;
    }
  }
  __syncthreads();

  // ---- softmax: wave w handles head w ----
  {
    const int h = tid >> 6, lane = tid & 63;
    float vals[8]; float m = -3.0e38f;
    #pragma unroll
    for (int r = 0; r < 8; ++r) { vals[r] = sA[h][lane + 64*r]; m = fmaxf(m, vals[r]); }
    #pragma unroll
    for (int off = 32; off; off >>= 1) m = fmaxf(m, __shfl_xor(m, off, 64));
    float ssum = 0.f;
    #pragma unroll
    for (int r = 0; r < 8; ++r) { vals[r] = __expf(vals[r] - m); ssum += vals[r]; }
    #pragma unroll
    for (int off = 32; off; off >>= 1) ssum += __shfl_xor(ssum, off, 64);
    const float inv = 1.0f / ssum;
    #pragma unroll
    for (int r = 0; r < 8; ++r) sA[h][lane + 64*r] = vals[r] * inv;
  }
  __syncthreads();

  // ---- o (threads 0..127) and o_pt (threads 128..415) ----
  if (tid < 128) {
    const int h = tid >> 4;
    float acc = 0.f;
    #pragma unroll 4
    for (int j = 0; j < NN; ++j)
      acc = fmaf(sA[h][j], v[(size_t)(b*NN + j)*128 + tid], acc);
    feats[(size_t)row*1536 + tid] = acc;
  } else if (tid < 416) {
    const int idx = tid - 128;             // h*36 + p*3 + x
    const int h = idx / 36, r2 = idx % 36, p = r2 / 3, x = r2 % 3;
    float acc = 0.f;
    #pragma unroll 4
    for (int j = 0; j < NN; ++j)
      acc = fmaf(sA[h][j], vp[(size_t)(b*NN + j)*288 + idx], acc);
    acc -= sT[x];
    sOPT[idx] = acc;
    feats[(size_t)row*1536 + 128 + x*96 + h*12 + p] = acc;
  }
  __syncthreads();

  // ---- o_pt norms ----
  if (tid < 96) {
    float xx = sOPT[tid*3], yy = sOPT[tid*3+1], zz = sOPT[tid*3+2];
    feats[(size_t)row*1536 + 416 + tid] = sqrtf(xx*xx + yy*yy + zz*zz + F_EPS);
  }

  // ---- o_pair: wave w = head w, float4 loads, 2 j-rows per iteration ----
  {
    const int h = tid >> 6, l = tid & 63;
    const int jh = l >> 5, z4 = l & 31;
    const float4* pr4 = (const float4*)(pair + ((size_t)(b*NN + i)) * NN * DCZ);
    float4 acc = {0.f, 0.f, 0.f, 0.f};
    #pragma unroll 4
    for (int it = 0; it < 256; ++it) {
      const int j = it*2 + jh;
      float a = sA[h][j];
      float4 p = pr4[(size_t)j*32 + z4];
      acc.x = fmaf(a, p.x, acc.x);
      acc.y = fmaf(a, p.y, acc.y);
      acc.z = fmaf(a, p.z, acc.z);
      acc.w = fmaf(a, p.w, acc.w);
    }
    acc.x += __shfl_xor(acc.x, 32);
    acc.y += __shfl_xor(acc.y, 32);
    acc.z += __shfl_xor(acc.z, 32);
    acc.w += __shfl_xor(acc.w, 32);
    if (jh == 0) {
      *(float4*)(feats + (size_t)row*1536 + 512 + h*128 + z4*4) = acc;
    }
  }
}

// ---------------------------------------------------------------------------
// Kernel 3: out = (seqs + feats @ Wout + bout) * mask
// 8 rows per block, 2 col-halves, 256 threads.
// ---------------------------------------------------------------------------
__global__ __launch_bounds__(256) void k_out(
    const float* __restrict__ Wout, const float* __restrict__ bout,
    const float* __restrict__ seqs, const float* __restrict__ mask,
    const float* __restrict__ ws, float* __restrict__ out)
{
  const int rg = blockIdx.x >> 1;
  const int ch = blockIdx.x & 1;
  const int tid = threadIdx.x;
  const int c = ch*256 + tid;
  const float* feats = ws + OFF_FT;

  __shared__ float s[8][1536];   // 48 KB
  for (int idx = tid; idx < 8*1536; idx += 256) {
    int r = idx / 1536, k0 = idx % 1536;
    s[r][k0] = feats[(size_t)(rg*8 + r)*1536 + k0];
  }
  __syncthreads();

  float acc[8];
  #pragma unroll
  for (int r = 0; r < 8; ++r) acc[r] = bout[c];
  for (int k0 = 0; k0 < 1536; k0 += 4) {
    float w0 = Wout[(size_t)(k0+0)*512 + c];
    float w1 = Wout[(size_t)(k0+1)*512 + c];
    float w2 = Wout[(size_t)(k0+2)*512 + c];
    float w3 = Wout[(size_t)(k0+3)*512 + c];
    #pragma unroll
    for (int r = 0; r < 8; ++r) {
      float4 sv = *(const float4*)&s[r][k0];
      acc[r] = fmaf(sv.x, w0, fmaf(sv.y, w1, fmaf(sv.z, w2, fmaf(sv.w, w3, acc[r]))));
    }
  }
  #pragma unroll
  for (int r = 0; r < 8; ++r) {
    size_t row = (size_t)rg*8 + r;
    out[row*512 + c] = (seqs[row*512 + c] + acc[r]) * mask[row];
  }
}

// ---------------------------------------------------------------------------
extern "C" void kernel_launch(void* const* d_in, const int* in_sizes, int n_in,
                              void* d_out, int out_size, void* d_ws, size_t ws_size,
                              hipStream_t stream)
{
  const float* seqs   = (const float*)d_in[0];
  const float* pair   = (const float*)d_in[1];
  const float* x_t    = (const float*)d_in[2];
  const float* mask   = (const float*)d_in[3];
  const float* Wq     = (const float*)d_in[4];
  const float* bq     = (const float*)d_in[5];
  const float* Wkv    = (const float*)d_in[6];
  const float* bkv    = (const float*)d_in[7];
  const float* Wqp    = (const float*)d_in[8];
  const float* bqp    = (const float*)d_in[9];
  const float* Wkvp   = (const float*)d_in[10];
  const float* bkvp   = (const float*)d_in[11];
  const float* Wb     = (const float*)d_in[12];
  const float* bb     = (const float*)d_in[13];
  const float* head_w = (const float*)d_in[14];
  const float* Wout   = (const float*)d_in[15];
  const float* bout   = (const float*)d_in[16];
  float* out = (float*)d_out;
  float* ws  = (float*)d_ws;

  hipLaunchKernelGGL(k_proj, dim3(NB*NN/4), dim3(512), 0, stream,
                     seqs, x_t, mask, Wq, bq, Wkv, bkv, Wqp, bqp, Wkvp, bkvp, ws);
  hipLaunchKernelGGL(k_attn, dim3(NB*NN), dim3(512), 0, stream,
                     pair, x_t, mask, head_w, Wb, bb, ws);
  hipLaunchKernelGGL(k_out, dim3(NB*NN/8*2), dim3(256), 0, stream,
                     Wout, bout, seqs, mask, ws, out);
}

// Round 3
// 820.141 us; speedup vs baseline: 1.7438x; 1.2517x over previous
//
#include <hip/hip_runtime.h>
#include <hip/hip_bf16.h>
#include <math.h>

// Problem constants
#define NB 2
#define NN 512
#define DCS 512
#define DCZ 128
#define NH 8
#define DC 16
#define NPQ 8
#define NPV 12

static constexpr float W_L  = 0.14433756729740643f;  // sqrt(1/(3*16))
static constexpr float W_C  = 0.09622504486493764f;  // sqrt(1/(3*36))
static constexpr float S13  = 0.57735026918962576f;  // sqrt(1/3)
static constexpr float F_INF = 100000.0f;
static constexpr float F_EPS = 1e-8f;

// workspace float offsets (same sizes as before; v and vp are now transposed)
static constexpr size_t OFF_Q   = 0;          // 2*512*128
static constexpr size_t OFF_K   = 131072;     // 2*512*128
static constexpr size_t OFF_VT  = 262144;     // 2*128*512  (vT[b][c][j])
static constexpr size_t OFF_QP  = 393216;     // 2*512*192
static constexpr size_t OFF_KP  = 589824;     // 2*512*192
static constexpr size_t OFF_VPT = 786432;     // 2*288*512  (vpT[b][idx][j])
static constexpr size_t OFF_FT  = 1081344;    // 2*512*1536

// ---------------------------------------------------------------------------
// Kernel 1: projections. 4 rows/block, 320 threads; thread = one col-quad.
// ---------------------------------------------------------------------------
__global__ __launch_bounds__(320) void k_proj(
    const float* __restrict__ seqs, const float* __restrict__ x_t, const float* __restrict__ mask,
    const float* __restrict__ Wq,  const float* __restrict__ bq,
    const float* __restrict__ Wkv, const float* __restrict__ bkv,
    const float* __restrict__ Wqp, const float* __restrict__ bqp,
    const float* __restrict__ Wkvp,const float* __restrict__ bkvp,
    float* __restrict__ ws)
{
  const int r0 = blockIdx.x * 4;
  __shared__ float s[4][DCS];     // 8 KB
  __shared__ float t[4][3];
  {
    float4* s4 = (float4*)s;
    const float4* src4 = (const float4*)(seqs + (size_t)r0 * DCS);
    for (int idx = threadIdx.x; idx < 512; idx += 320) s4[idx] = src4[idx];
    if (threadIdx.x < 12) {
      int r = threadIdx.x / 3, x = threadIdx.x % 3;
      t[r][x] = x_t[(r0 + r)*3 + x] * mask[r0 + r];
    }
  }
  __syncthreads();

  const int qd = threadIdx.x;
  if (qd >= 264) return;

  float* q   = ws + OFF_Q;
  float* kk  = ws + OFF_K;
  float* vT  = ws + OFF_VT;
  float* qp  = ws + OFF_QP;
  float* kp  = ws + OFF_KP;
  float* vpT = ws + OFF_VPT;

  const float* W; const float* bias; int c, ncol, kind;
  if (qd < 32)       { W = Wq;   bias = bq;   c = qd*4;       ncol = 128; kind = 0; }
  else if (qd < 96)  { W = Wkv;  bias = bkv;  c = (qd-32)*4;  ncol = 256; kind = 1; }
  else if (qd < 144) { W = Wqp;  bias = bqp;  c = (qd-96)*4;  ncol = 192; kind = 2; }
  else               { W = Wkvp; bias = bkvp; c = (qd-144)*4; ncol = 480; kind = 3; }

  const float4 b4 = *(const float4*)(bias + c);
  float4 a0 = b4, a1 = b4, a2 = b4, a3 = b4;
  const float* Wp = W + c;

  for (int k = 0; k < DCS; k += 4) {
    float4 w0 = *(const float4*)(Wp + (size_t)(k+0)*ncol);
    float4 w1 = *(const float4*)(Wp + (size_t)(k+1)*ncol);
    float4 w2 = *(const float4*)(Wp + (size_t)(k+2)*ncol);
    float4 w3 = *(const float4*)(Wp + (size_t)(k+3)*ncol);
    float4 s0 = *(const float4*)&s[0][k];
    float4 s1 = *(const float4*)&s[1][k];
    float4 s2 = *(const float4*)&s[2][k];
    float4 s3 = *(const float4*)&s[3][k];
    a0.x = fmaf(s0.x,w0.x, fmaf(s0.y,w1.x, fmaf(s0.z,w2.x, fmaf(s0.w,w3.x, a0.x))));
    a0.y = fmaf(s0.x,w0.y, fmaf(s0.y,w1.y, fmaf(s0.z,w2.y, fmaf(s0.w,w3.y, a0.y))));
    a0.z = fmaf(s0.x,w0.z, fmaf(s0.y,w1.z, fmaf(s0.z,w2.z, fmaf(s0.w,w3.z, a0.z))));
    a0.w = fmaf(s0.x,w0.w, fmaf(s0.y,w1.w, fmaf(s0.z,w2.w, fmaf(s0.w,w3.w, a0.w))));
    a1.x = fmaf(s1.x,w0.x, fmaf(s1.y,w1.x, fmaf(s1.z,w2.x, fmaf(s1.w,w3.x, a1.x))));
    a1.y = fmaf(s1.x,w0.y, fmaf(s1.y,w1.y, fmaf(s1.z,w2.y, fmaf(s1.w,w3.y, a1.y))));
    a1.z = fmaf(s1.x,w0.z, fmaf(s1.y,w1.z, fmaf(s1.z,w2.z, fmaf(s1.w,w3.z, a1.z))));
    a1.w = fmaf(s1.x,w0.w, fmaf(s1.y,w1.w, fmaf(s1.z,w2.w, fmaf(s1.w,w3.w, a1.w))));
    a2.x = fmaf(s2.x,w0.x, fmaf(s2.y,w1.x, fmaf(s2.z,w2.x, fmaf(s2.w,w3.x, a2.x))));
    a2.y = fmaf(s2.x,w0.y, fmaf(s2.y,w1.y, fmaf(s2.z,w2.y, fmaf(s2.w,w3.y, a2.y))));
    a2.z = fmaf(s2.x,w0.z, fmaf(s2.y,w1.z, fmaf(s2.z,w2.z, fmaf(s2.w,w3.z, a2.z))));
    a2.w = fmaf(s2.x,w0.w, fmaf(s2.y,w1.w, fmaf(s2.z,w2.w, fmaf(s2.w,w3.w, a2.w))));
    a3.x = fmaf(s3.x,w0.x, fmaf(s3.y,w1.x, fmaf(s3.z,w2.x, fmaf(s3.w,w3.x, a3.x))));
    a3.y = fmaf(s3.x,w0.y, fmaf(s3.y,w1.y, fmaf(s3.z,w2.y, fmaf(s3.w,w3.y, a3.y))));
    a3.z = fmaf(s3.x,w0.z, fmaf(s3.y,w1.z, fmaf(s3.z,w2.z, fmaf(s3.w,w3.z, a3.z))));
    a3.w = fmaf(s3.x,w0.w, fmaf(s3.y,w1.w, fmaf(s3.z,w2.w, fmaf(s3.w,w3.w, a3.w))));
  }

  float4 accs[4] = {a0, a1, a2, a3};
  #pragma unroll
  for (int r = 0; r < 4; ++r) {
    const int row = r0 + r;
    const int bb_ = row >> 9, j = row & 511;
    float4 acc = accs[r];
    float vals[4] = {acc.x, acc.y, acc.z, acc.w};
    if (kind == 0) {
      *(float4*)(q + (size_t)row*128 + c) = acc;
    } else if (kind == 1) {
      int h = c >> 5, rr = c & 31;
      if (rr < 16) {
        *(float4*)(kk + (size_t)row*128 + h*16 + rr) = acc;
      } else {
        int cp = h*16 + (rr - 16);
        #pragma unroll
        for (int u = 0; u < 4; ++u)
          vT[((size_t)bb_*128 + cp + u)*512 + j] = vals[u];
      }
    } else if (kind == 2) {
      #pragma unroll
      for (int u = 0; u < 4; ++u) {
        int cc = c + u, x = cc >> 6, rem = cc & 63, h = rem >> 3, p = rem & 7;
        qp[(size_t)row*192 + (h*8+p)*3 + x] = vals[u] + t[r][x];
      }
    } else {
      #pragma unroll
      for (int u = 0; u < 4; ++u) {
        int cc = c + u, x = cc / 160, rem = cc % 160, h = rem / 20, p = rem % 20;
        float vv = vals[u] + t[r][x];
        if (p < 8) kp[(size_t)row*192 + (h*8+p)*3 + x] = vv;
        else       vpT[((size_t)bb_*288 + (h*36 + (p-8)*3 + x))*512 + j] = vv;
      }
    }
  }
}

// ---------------------------------------------------------------------------
// Kernel 2: attention, one block per (b,i), 512 threads, all 8 heads fused.
// Bias computed inline; o_pair j-partitioned across waves (pair read once).
// ---------------------------------------------------------------------------
__global__ __launch_bounds__(512) void k_attn(
    const float* __restrict__ pair, const float* __restrict__ x_t, const float* __restrict__ mask,
    const float* __restrict__ head_w, const float* __restrict__ Wb, const float* __restrict__ bb,
    float* __restrict__ ws)
{
  const int row = blockIdx.x;
  const int b = row >> 9, i = row & 511;
  const int tid = threadIdx.x;

  const float* q   = ws + OFF_Q;
  const float* kk  = ws + OFF_K;
  const float* vT  = ws + OFF_VT;
  const float* qp  = ws + OFF_QP;
  const float* kp  = ws + OFF_KP;
  const float* vpT = ws + OFF_VPT;
  float* feats = ws + OFF_FT;

  __shared__ float sA[NH][NN];     // 16 KB
  __shared__ float sWb[NH * DCZ]; // 4 KB, [h][z]
  __shared__ float sOP[NH * DCZ]; // 4 KB o_pair accumulator
  __shared__ float sQ[128];
  __shared__ float sQP[192];
  __shared__ float sOPT[288];
  __shared__ float sHW[NH];
  __shared__ float sT[3];
  __shared__ float sMi;

  for (int idx = tid; idx < NH*DCZ; idx += 512) {
    int h = idx >> 7, z = idx & 127;
    sWb[idx] = Wb[z*NH + h];
    sOP[idx] = 0.f;
  }
  if (tid < 128) sQ[tid] = q[(size_t)row*128 + tid];
  else if (tid < 320) sQP[tid-128] = qp[(size_t)row*192 + (tid-128)];
  else if (tid < 328) {
    float x = head_w[tid-320];
    float sp = (x > 20.f) ? x : log1pf(expf(x));
    sHW[tid-320] = 0.5f * W_C * sp;
  }
  else if (tid == 328) sMi = mask[row];
  else if (tid >= 336 && tid < 339) sT[tid-336] = x_t[row*3 + (tid-336)] * mask[row];
  __syncthreads();

  // ---- logits (incl. inline pair-bias): thread j computes all 8 heads ----
  {
    const int j = tid;
    const float mj = mask[b*NN + j];
    const float mterm = F_INF * (sMi * mj - 1.0f);

    float accb[NH];
    #pragma unroll
    for (int h = 0; h < NH; ++h) accb[h] = bb[h];
    const float4* prow4 = (const float4*)(pair + ((size_t)(b*NN + i)*NN + j) * DCZ);
    const float4* sWb4  = (const float4*)sWb;
    #pragma unroll 4
    for (int zc = 0; zc < 32; ++zc) {
      float4 pv = prow4[zc];
      #pragma unroll
      for (int h = 0; h < NH; ++h) {
        float4 w = sWb4[h*32 + zc];
        accb[h] = fmaf(pv.x, w.x, fmaf(pv.y, w.y, fmaf(pv.z, w.z, fmaf(pv.w, w.w, accb[h]))));
      }
    }

    const float* kr  = kk + (size_t)(b*NN + j) * 128;
    const float* kpr = kp + (size_t)(b*NN + j) * 192;
    #pragma unroll
    for (int h = 0; h < NH; ++h) {
      float dot = 0.f;
      const float4* k4 = (const float4*)(kr + h*16);
      const float4* q4 = (const float4*)(sQ + h*16);
      #pragma unroll
      for (int u = 0; u < 4; ++u) {
        float4 a = q4[u], cc = k4[u];
        dot += a.x*cc.x + a.y*cc.y + a.z*cc.z + a.w*cc.w;
      }
      float d2 = 0.f;
      const float4* qp4 = (const float4*)(sQP + h*24);
      const float4* kp4 = (const float4*)(kpr + h*24);
      #pragma unroll
      for (int u = 0; u < 6; ++u) {
        float4 a = qp4[u], cc = kp4[u];
        float dx = a.x-cc.x, dy = a.y-cc.y, dz = a.z-cc.z, dw = a.w-cc.w;
        d2 += dx*dx + dy*dy + dz*dz + dw*dw;
      }
      sA[h][j] = W_L * dot + S13 * accb[h] - sHW[h]*d2 + mterm;
    }
  }
  __syncthreads();

  // ---- softmax: wave w handles head w ----
  {
    const int h = tid >> 6, lane = tid & 63;
    float vals[8]; float m = -3.0e38f;
    #pragma unroll
    for (int r = 0; r < 8; ++r) { vals[r] = sA[h][lane + 64*r]; m = fmaxf(m, vals[r]); }
    #pragma unroll
    for (int off = 32; off; off >>= 1) m = fmaxf(m, __shfl_xor(m, off, 64));
    float ssum = 0.f;
    #pragma unroll
    for (int r = 0; r < 8; ++r) { vals[r] = __expf(vals[r] - m); ssum += vals[r]; }
    #pragma unroll
    for (int off = 32; off; off >>= 1) ssum += __shfl_xor(ssum, off, 64);
    const float inv = 1.0f / ssum;
    #pragma unroll
    for (int r = 0; r < 8; ++r) sA[h][lane + 64*r] = vals[r] * inv;
  }
  __syncthreads();

  // ---- o (threads 0..127) and o_pt (threads 128..415), contiguous vT/vpT ----
  if (tid < 128) {
    const int h = tid >> 4;
    const float4* vr = (const float4*)(vT + ((size_t)b*128 + tid)*512);
    float acc = 0.f;
    #pragma unroll 4
    for (int jg = 0; jg < 128; ++jg) {
      float4 pv = vr[jg];
      float4 av = *(const float4*)&sA[h][jg*4];
      acc = fmaf(pv.x, av.x, fmaf(pv.y, av.y, fmaf(pv.z, av.z, fmaf(pv.w, av.w, acc))));
    }
    feats[(size_t)row*1536 + tid] = acc;
  } else if (tid < 416) {
    const int idx = tid - 128;             // h*36 + p*3 + x
    const int h = idx / 36, r2 = idx % 36, x = r2 % 3;
    const float4* vr = (const float4*)(vpT + ((size_t)b*288 + idx)*512);
    float acc = 0.f;
    #pragma unroll 4
    for (int jg = 0; jg < 128; ++jg) {
      float4 pv = vr[jg];
      float4 av = *(const float4*)&sA[h][jg*4];
      acc = fmaf(pv.x, av.x, fmaf(pv.y, av.y, fmaf(pv.z, av.z, fmaf(pv.w, av.w, acc))));
    }
    acc -= sT[x];
    sOPT[idx] = acc;
    feats[(size_t)row*1536 + 128 + x*96 + h*12 + (r2/3)] = acc;
  }
  __syncthreads();

  // ---- o_pt norms ----
  if (tid < 96) {
    float xx = sOPT[tid*3], yy = sOPT[tid*3+1], zz = sOPT[tid*3+2];
    feats[(size_t)row*1536 + 416 + tid] = sqrtf(xx*xx + yy*yy + zz*zz + F_EPS);
  }

  // ---- o_pair: wave w owns j in [w*64, w*64+64), all 8 heads; pair read once ----
  {
    const int w = tid >> 6, l = tid & 63;
    const int jh = l >> 5, z4 = l & 31;
    const float4* pr4 = (const float4*)(pair + ((size_t)(b*NN + i)) * NN * DCZ);
    float4 acc[NH];
    #pragma unroll
    for (int h = 0; h < NH; ++h) acc[h] = make_float4(0.f,0.f,0.f,0.f);
    const int jbase = w*64;
    #pragma unroll 2
    for (int it = 0; it < 32; ++it) {
      const int j = jbase + it*2 + jh;
      float4 p = pr4[(size_t)j*32 + z4];
      #pragma unroll
      for (int h = 0; h < NH; ++h) {
        float a = sA[h][j];
        acc[h].x = fmaf(a, p.x, acc[h].x);
        acc[h].y = fmaf(a, p.y, acc[h].y);
        acc[h].z = fmaf(a, p.z, acc[h].z);
        acc[h].w = fmaf(a, p.w, acc[h].w);
      }
    }
    #pragma unroll
    for (int h = 0; h < NH; ++h) {
      acc[h].x += __shfl_xor(acc[h].x, 32);
      acc[h].y += __shfl_xor(acc[h].y, 32);
      acc[h].z += __shfl_xor(acc[h].z, 32);
      acc[h].w += __shfl_xor(acc[h].w, 32);
    }
    if (jh == 0) {
      #pragma unroll
      for (int h = 0; h < NH; ++h) {
        float* dst = &sOP[h*DCZ + z4*4];
        atomicAdd(dst+0, acc[h].x);
        atomicAdd(dst+1, acc[h].y);
        atomicAdd(dst+2, acc[h].z);
        atomicAdd(dst+3, acc[h].w);
      }
    }
  }
  __syncthreads();
  for (int idx = tid; idx < NH*DCZ; idx += 512)
    feats[(size_t)row*1536 + 512 + idx] = sOP[idx];
}

// ---------------------------------------------------------------------------
// Kernel 3: out = (seqs + feats @ Wout + bout) * mask
// 8 rows/block, 512 threads = 128 col-quads x 4 K-splits, LDS partial reduce.
// ---------------------------------------------------------------------------
__global__ __launch_bounds__(512) void k_out(
    const float* __restrict__ Wout, const float* __restrict__ bout,
    const float* __restrict__ seqs, const float* __restrict__ mask,
    const float* __restrict__ ws, float* __restrict__ out)
{
  const int r0 = blockIdx.x * 8;
  const int tid = threadIdx.x;
  const float* feats = ws + OFF_FT;

  __shared__ float s[8][1536];   // 48 KB
  {
    float4* s4 = (float4*)s;
    const float4* f4 = (const float4*)(feats + (size_t)r0*1536);
    for (int idx = tid; idx < 3072; idx += 512) s4[idx] = f4[idx];
  }
  __syncthreads();

  const int qd = tid & 127, kh = tid >> 7;
  const int c = qd*4;
  float4 acc[8];
  #pragma unroll
  for (int r = 0; r < 8; ++r) acc[r] = make_float4(0.f,0.f,0.f,0.f);

  const int kb = kh*384;
  const float* Wp = Wout + c;
  for (int k = kb; k < kb + 384; k += 4) {
    float4 w0 = *(const float4*)(Wp + (size_t)(k+0)*512);
    float4 w1 = *(const float4*)(Wp + (size_t)(k+1)*512);
    float4 w2 = *(const float4*)(Wp + (size_t)(k+2)*512);
    float4 w3 = *(const float4*)(Wp + (size_t)(k+3)*512);
    #pragma unroll
    for (int r = 0; r < 8; ++r) {
      float4 sv = *(const float4*)&s[r][k];
      acc[r].x = fmaf(sv.x,w0.x, fmaf(sv.y,w1.x, fmaf(sv.z,w2.x, fmaf(sv.w,w3.x, acc[r].x))));
      acc[r].y = fmaf(sv.x,w0.y, fmaf(sv.y,w1.y, fmaf(sv.z,w2.y, fmaf(sv.w,w3.y, acc[r].y))));
      acc[r].z = fmaf(sv.x,w0.z, fmaf(sv.y,w1.z, fmaf(sv.z,w2.z, fmaf(sv.w,w3.z, acc[r].z))));
      acc[r].w = fmaf(sv.x,w0.w, fmaf(sv.y,w1.w, fmaf(sv.z,w2.w, fmaf(sv.w,w3.w, acc[r].w))));
    }
  }
  __syncthreads();   // everyone done reading s; overlay as partial buffer

  float* part = &s[0][0];   // [3][8][128] float4 = 48 KB exactly
  if (kh > 0) {
    #pragma unroll
    for (int r = 0; r < 8; ++r)
      *(float4*)&part[(((kh-1)*8 + r)*128 + qd)*4] = acc[r];
  }
  __syncthreads();
  if (kh == 0) {
    #pragma unroll
    for (int g = 0; g < 3; ++g) {
      #pragma unroll
      for (int r = 0; r < 8; ++r) {
        float4 p = *(const float4*)&part[((g*8 + r)*128 + qd)*4];
        acc[r].x += p.x; acc[r].y += p.y; acc[r].z += p.z; acc[r].w += p.w;
      }
    }
    float4 bv = *(const float4*)(bout + c);
    #pragma unroll
    for (int r = 0; r < 8; ++r) {
      const int row = r0 + r;
      const float m = mask[row];
      float4 sq = *(const float4*)(seqs + (size_t)row*512 + c);
      float4 o;
      o.x = (sq.x + bv.x + acc[r].x) * m;
      o.y = (sq.y + bv.y + acc[r].y) * m;
      o.z = (sq.z + bv.z + acc[r].z) * m;
      o.w = (sq.w + bv.w + acc[r].w) * m;
      *(float4*)(out + (size_t)row*512 + c) = o;
    }
  }
}

// ---------------------------------------------------------------------------
extern "C" void kernel_launch(void* const* d_in, const int* in_sizes, int n_in,
                              void* d_out, int out_size, void* d_ws, size_t ws_size,
                              hipStream_t stream)
{
  const float* seqs   = (const float*)d_in[0];
  const float* pair   = (const float*)d_in[1];
  const float* x_t    = (const float*)d_in[2];
  const float* mask   = (const float*)d_in[3];
  const float* Wq     = (const float*)d_in[4];
  const float* bq     = (const float*)d_in[5];
  const float* Wkv    = (const float*)d_in[6];
  const float* bkv    = (const float*)d_in[7];
  const float* Wqp    = (const float*)d_in[8];
  const float* bqp    = (const float*)d_in[9];
  const float* Wkvp   = (const float*)d_in[10];
  const float* bkvp   = (const float*)d_in[11];
  const float* Wb     = (const float*)d_in[12];
  const float* bb     = (const float*)d_in[13];
  const float* head_w = (const float*)d_in[14];
  const float* Wout   = (const float*)d_in[15];
  const float* bout   = (const float*)d_in[16];
  float* out = (float*)d_out;
  float* ws  = (float*)d_ws;

  hipLaunchKernelGGL(k_proj, dim3(NB*NN/4), dim3(320), 0, stream,
                     seqs, x_t, mask, Wq, bq, Wkv, bkv, Wqp, bqp, Wkvp, bkvp, ws);
  hipLaunchKernelGGL(k_attn, dim3(NB*NN), dim3(512), 0, stream,
                     pair, x_t, mask, head_w, Wb, bb, ws);
  hipLaunchKernelGGL(k_out, dim3(NB*NN/8), dim3(512), 0, stream,
                     Wout, bout, seqs, mask, ws, out);
}

// Round 4
// 730.337 us; speedup vs baseline: 1.9582x; 1.1230x over previous
//
#include <hip/hip_runtime.h>
#include <hip/hip_bf16.h>
#include <math.h>

// Problem constants
#define NB 2
#define NN 512
#define DCS 512
#define DCZ 128
#define NH 8
#define DC 16
#define NPQ 8
#define NPV 12

static constexpr float W_L  = 0.14433756729740643f;  // sqrt(1/(3*16))
static constexpr float W_C  = 0.09622504486493764f;  // sqrt(1/(3*36))
static constexpr float S13  = 0.57735026918962576f;  // sqrt(1/3)
static constexpr float F_INF = 100000.0f;
static constexpr float F_EPS = 1e-8f;

// workspace float offsets
static constexpr size_t OFF_Q   = 0;          // 2*512*128
static constexpr size_t OFF_K   = 131072;     // 2*512*128
static constexpr size_t OFF_VT  = 262144;     // 2*128*512  (vT[b][c][j])
static constexpr size_t OFF_QP  = 393216;     // 2*512*192
static constexpr size_t OFF_KP  = 589824;     // 2*512*192
static constexpr size_t OFF_VPT = 786432;     // 2*288*512  (vpT[b][idx][j])
static constexpr size_t OFF_FT  = 1081344;    // 2*512*1536

// ---------------------------------------------------------------------------
// Kernel 1: projections. 2 rows/block, 528 threads = 264 col-quads x 2 K-split.
// ---------------------------------------------------------------------------
__global__ __launch_bounds__(528) void k_proj(
    const float* __restrict__ seqs, const float* __restrict__ x_t, const float* __restrict__ mask,
    const float* __restrict__ Wq,  const float* __restrict__ bq,
    const float* __restrict__ Wkv, const float* __restrict__ bkv,
    const float* __restrict__ Wqp, const float* __restrict__ bqp,
    const float* __restrict__ Wkvp,const float* __restrict__ bkvp,
    float* __restrict__ ws)
{
  const int r0 = blockIdx.x * 2;
  const int tid = threadIdx.x;
  __shared__ float s[2][DCS];        // 4 KB
  __shared__ float t[2][3];
  __shared__ float pb[2][4][264];    // 8.25 KB partials, conflict-free layout
  {
    float4* s4 = (float4*)s;
    const float4* src4 = (const float4*)(seqs + (size_t)r0 * DCS);
    for (int idx = tid; idx < 256; idx += 528) s4[idx] = src4[idx];
    if (tid < 6) {
      int r = tid / 3, x = tid % 3;
      t[r][x] = x_t[(r0 + r)*3 + x] * mask[r0 + r];
    }
  }
  __syncthreads();

  const int kh = (tid >= 264) ? 1 : 0;
  const int qd = tid - kh*264;

  float* q   = ws + OFF_Q;
  float* kk  = ws + OFF_K;
  float* vT  = ws + OFF_VT;
  float* qp  = ws + OFF_QP;
  float* kp  = ws + OFF_KP;
  float* vpT = ws + OFF_VPT;

  const float* W; const float* bias; int c, ncol, kind;
  if (qd < 32)       { W = Wq;   bias = bq;   c = qd*4;       ncol = 128; kind = 0; }
  else if (qd < 96)  { W = Wkv;  bias = bkv;  c = (qd-32)*4;  ncol = 256; kind = 1; }
  else if (qd < 144) { W = Wqp;  bias = bqp;  c = (qd-96)*4;  ncol = 192; kind = 2; }
  else               { W = Wkvp; bias = bkvp; c = (qd-144)*4; ncol = 480; kind = 3; }

  float4 a0, a1;
  if (kh == 0) { a0 = *(const float4*)(bias + c); a1 = a0; }
  else         { a0 = make_float4(0.f,0.f,0.f,0.f); a1 = a0; }
  const float* Wp = W + c;
  const int kb = kh * 256;

  for (int k = kb; k < kb + 256; k += 4) {
    float4 w0 = *(const float4*)(Wp + (size_t)(k+0)*ncol);
    float4 w1 = *(const float4*)(Wp + (size_t)(k+1)*ncol);
    float4 w2 = *(const float4*)(Wp + (size_t)(k+2)*ncol);
    float4 w3 = *(const float4*)(Wp + (size_t)(k+3)*ncol);
    float4 s0 = *(const float4*)&s[0][k];
    float4 s1 = *(const float4*)&s[1][k];
    a0.x = fmaf(s0.x,w0.x, fmaf(s0.y,w1.x, fmaf(s0.z,w2.x, fmaf(s0.w,w3.x, a0.x))));
    a0.y = fmaf(s0.x,w0.y, fmaf(s0.y,w1.y, fmaf(s0.z,w2.y, fmaf(s0.w,w3.y, a0.y))));
    a0.z = fmaf(s0.x,w0.z, fmaf(s0.y,w1.z, fmaf(s0.z,w2.z, fmaf(s0.w,w3.z, a0.z))));
    a0.w = fmaf(s0.x,w0.w, fmaf(s0.y,w1.w, fmaf(s0.z,w2.w, fmaf(s0.w,w3.w, a0.w))));
    a1.x = fmaf(s1.x,w0.x, fmaf(s1.y,w1.x, fmaf(s1.z,w2.x, fmaf(s1.w,w3.x, a1.x))));
    a1.y = fmaf(s1.x,w0.y, fmaf(s1.y,w1.y, fmaf(s1.z,w2.y, fmaf(s1.w,w3.y, a1.y))));
    a1.z = fmaf(s1.x,w0.z, fmaf(s1.y,w1.z, fmaf(s1.z,w2.z, fmaf(s1.w,w3.z, a1.z))));
    a1.w = fmaf(s1.x,w0.w, fmaf(s1.y,w1.w, fmaf(s1.z,w2.w, fmaf(s1.w,w3.w, a1.w))));
  }

  if (kh == 1) {
    pb[0][0][qd] = a0.x; pb[0][1][qd] = a0.y; pb[0][2][qd] = a0.z; pb[0][3][qd] = a0.w;
    pb[1][0][qd] = a1.x; pb[1][1][qd] = a1.y; pb[1][2][qd] = a1.z; pb[1][3][qd] = a1.w;
  }
  __syncthreads();
  if (kh == 0) {
    a0.x += pb[0][0][qd]; a0.y += pb[0][1][qd]; a0.z += pb[0][2][qd]; a0.w += pb[0][3][qd];
    a1.x += pb[1][0][qd]; a1.y += pb[1][1][qd]; a1.z += pb[1][2][qd]; a1.w += pb[1][3][qd];
    float4 accs[2] = {a0, a1};
    #pragma unroll
    for (int r = 0; r < 2; ++r) {
      const int row = r0 + r;
      const int bb_ = row >> 9, j = row & 511;
      float4 acc = accs[r];
      float vals[4] = {acc.x, acc.y, acc.z, acc.w};
      if (kind == 0) {
        *(float4*)(q + (size_t)row*128 + c) = acc;
      } else if (kind == 1) {
        int h = c >> 5, rr = c & 31;
        if (rr < 16) {
          *(float4*)(kk + (size_t)row*128 + h*16 + rr) = acc;
        } else {
          int cp = h*16 + (rr - 16);
          #pragma unroll
          for (int u = 0; u < 4; ++u)
            vT[((size_t)bb_*128 + cp + u)*512 + j] = vals[u];
        }
      } else if (kind == 2) {
        #pragma unroll
        for (int u = 0; u < 4; ++u) {
          int cc = c + u, x = cc >> 6, rem = cc & 63, h = rem >> 3, p = rem & 7;
          qp[(size_t)row*192 + (h*8+p)*3 + x] = vals[u] + t[r][x];
        }
      } else {
        #pragma unroll
        for (int u = 0; u < 4; ++u) {
          int cc = c + u, x = cc / 160, rem = cc % 160, h = rem / 20, p = rem % 20;
          float vv = vals[u] + t[r][x];
          if (p < 8) kp[(size_t)row*192 + (h*8+p)*3 + x] = vv;
          else       vpT[((size_t)bb_*288 + (h*36 + (p-8)*3 + x))*512 + j] = vv;
        }
      }
    }
  }
}

// ---------------------------------------------------------------------------
// Kernel 2: attention, one block per 2 i-rows, 512 threads, all 8 heads fused.
// K/KP/vT/vpT reads amortized over 2 rows; o_pair lane-split by row.
// ---------------------------------------------------------------------------
__global__ __launch_bounds__(512) void k_attn(
    const float* __restrict__ pair, const float* __restrict__ x_t, const float* __restrict__ mask,
    const float* __restrict__ head_w, const float* __restrict__ Wb, const float* __restrict__ bb,
    float* __restrict__ ws)
{
  const int gid = blockIdx.x;
  const int b = gid >> 8;
  const int ii = (gid & 255) * 2;
  const int row0 = b*NN + ii;
  const int tid = threadIdx.x;

  const float* q   = ws + OFF_Q;
  const float* kk  = ws + OFF_K;
  const float* vT  = ws + OFF_VT;
  const float* qp  = ws + OFF_QP;
  const float* kp  = ws + OFF_KP;
  const float* vpT = ws + OFF_VPT;
  float* feats = ws + OFF_FT;

  __shared__ float sA[2][NH][NN];    // 32 KB
  __shared__ float sWb[NH * DCZ];    // 4 KB [h][z]
  __shared__ float sOP[2][NH * DCZ]; // 8 KB
  __shared__ float sQ[2][128];
  __shared__ float sQP[2][192];
  __shared__ float sOPT[2][288];
  __shared__ float sHW[NH];
  __shared__ float sT[2][3];
  __shared__ float sMi[2];

  for (int idx = tid; idx < NH*DCZ; idx += 512) {
    int h = idx >> 7, z = idx & 127;
    sWb[idx] = Wb[z*NH + h];
  }
  {
    float* sOPf = &sOP[0][0];
    for (int idx = tid; idx < 2*NH*DCZ; idx += 512) sOPf[idx] = 0.f;
  }
  for (int idx = tid; idx < 640; idx += 512) {
    if (idx < 256) sQ[idx>>7][idx&127] = q[(size_t)(row0 + (idx>>7))*128 + (idx&127)];
    else {
      int k2 = idx - 256; int r = k2/192, cc = k2%192;
      sQP[r][cc] = qp[(size_t)(row0+r)*192 + cc];
    }
  }
  if (tid < NH) {
    float x = head_w[tid];
    float sp = (x > 20.f) ? x : log1pf(expf(x));
    sHW[tid] = 0.5f * W_C * sp;
  } else if (tid >= 64 && tid < 66) {
    sMi[tid-64] = mask[row0 + (tid-64)];
  } else if (tid >= 128 && tid < 134) {
    int k2 = tid - 128; int r = k2/3, x = k2%3;
    sT[r][x] = x_t[(row0+r)*3 + x] * mask[row0+r];
  }
  __syncthreads();

  // ---- logits + inline pair-bias: thread j, both rows, all 8 heads ----
  {
    const int j = tid;
    const float mj = mask[b*NN + j];
    const float mterm0 = F_INF * (sMi[0]*mj - 1.0f);
    const float mterm1 = F_INF * (sMi[1]*mj - 1.0f);

    float accb0[NH], accb1[NH];
    #pragma unroll
    for (int h = 0; h < NH; ++h) { accb0[h] = bb[h]; accb1[h] = bb[h]; }
    const float4* pr0 = (const float4*)(pair + ((size_t)(row0+0)*NN + j) * DCZ);
    const float4* pr1 = (const float4*)(pair + ((size_t)(row0+1)*NN + j) * DCZ);
    const float4* sWb4 = (const float4*)sWb;
    #pragma unroll 2
    for (int zc = 0; zc < 32; ++zc) {
      float4 p0 = pr0[zc], p1 = pr1[zc];
      #pragma unroll
      for (int h = 0; h < NH; ++h) {
        float4 w = sWb4[h*32 + zc];
        accb0[h] = fmaf(p0.x, w.x, fmaf(p0.y, w.y, fmaf(p0.z, w.z, fmaf(p0.w, w.w, accb0[h]))));
        accb1[h] = fmaf(p1.x, w.x, fmaf(p1.y, w.y, fmaf(p1.z, w.z, fmaf(p1.w, w.w, accb1[h]))));
      }
    }

    const float* kr  = kk + (size_t)(b*NN + j) * 128;
    const float* kpr = kp + (size_t)(b*NN + j) * 192;
    #pragma unroll
    for (int h = 0; h < NH; ++h) {
      const float4* k4  = (const float4*)(kr + h*16);
      const float4* q04 = (const float4*)(&sQ[0][h*16]);
      const float4* q14 = (const float4*)(&sQ[1][h*16]);
      float dot0 = 0.f, dot1 = 0.f;
      #pragma unroll
      for (int u = 0; u < 4; ++u) {
        float4 kv = k4[u], a0 = q04[u], a1 = q14[u];
        dot0 += a0.x*kv.x + a0.y*kv.y + a0.z*kv.z + a0.w*kv.w;
        dot1 += a1.x*kv.x + a1.y*kv.y + a1.z*kv.z + a1.w*kv.w;
      }
      const float4* kp4  = (const float4*)(kpr + h*24);
      const float4* qp04 = (const float4*)(&sQP[0][h*24]);
      const float4* qp14 = (const float4*)(&sQP[1][h*24]);
      float d20 = 0.f, d21 = 0.f;
      #pragma unroll
      for (int u = 0; u < 6; ++u) {
        float4 kv = kp4[u], a0 = qp04[u], a1 = qp14[u];
        float dx0 = a0.x-kv.x, dy0 = a0.y-kv.y, dz0 = a0.z-kv.z, dw0 = a0.w-kv.w;
        float dx1 = a1.x-kv.x, dy1 = a1.y-kv.y, dz1 = a1.z-kv.z, dw1 = a1.w-kv.w;
        d20 += dx0*dx0 + dy0*dy0 + dz0*dz0 + dw0*dw0;
        d21 += dx1*dx1 + dy1*dy1 + dz1*dz1 + dw1*dw1;
      }
      sA[0][h][j] = W_L * dot0 + S13 * accb0[h] - sHW[h]*d20 + mterm0;
      sA[1][h][j] = W_L * dot1 + S13 * accb1[h] - sHW[h]*d21 + mterm1;
    }
  }
  __syncthreads();

  // ---- softmax: wave w handles head w for both rows ----
  {
    const int w = tid >> 6, lane = tid & 63;
    #pragma unroll
    for (int r = 0; r < 2; ++r) {
      float vals[8]; float m = -3.0e38f;
      #pragma unroll
      for (int u = 0; u < 8; ++u) { vals[u] = sA[r][w][lane + 64*u]; m = fmaxf(m, vals[u]); }
      #pragma unroll
      for (int off = 32; off; off >>= 1) m = fmaxf(m, __shfl_xor(m, off, 64));
      float ssum = 0.f;
      #pragma unroll
      for (int u = 0; u < 8; ++u) { vals[u] = __expf(vals[u] - m); ssum += vals[u]; }
      #pragma unroll
      for (int off = 32; off; off >>= 1) ssum += __shfl_xor(ssum, off, 64);
      const float inv = 1.0f / ssum;
      #pragma unroll
      for (int u = 0; u < 8; ++u) sA[r][w][lane + 64*u] = vals[u] * inv;
    }
  }
  __syncthreads();

  // ---- o (tid<128) and o_pt (128..415), vT/vpT loads reused for both rows ----
  if (tid < 128) {
    const int cc = tid, h = tid >> 4;
    const float4* vr = (const float4*)(vT + ((size_t)b*128 + cc)*512);
    float acc0 = 0.f, acc1 = 0.f;
    #pragma unroll 4
    for (int jg = 0; jg < 128; ++jg) {
      float4 pv = vr[jg];
      float4 a0 = *(const float4*)&sA[0][h][jg*4];
      float4 a1 = *(const float4*)&sA[1][h][jg*4];
      acc0 = fmaf(pv.x, a0.x, fmaf(pv.y, a0.y, fmaf(pv.z, a0.z, fmaf(pv.w, a0.w, acc0))));
      acc1 = fmaf(pv.x, a1.x, fmaf(pv.y, a1.y, fmaf(pv.z, a1.z, fmaf(pv.w, a1.w, acc1))));
    }
    feats[(size_t)(row0+0)*1536 + cc] = acc0;
    feats[(size_t)(row0+1)*1536 + cc] = acc1;
  } else if (tid < 416) {
    const int idx = tid - 128;             // h*36 + p*3 + x
    const int h = idx / 36, r2 = idx % 36, x = r2 % 3;
    const float4* vr = (const float4*)(vpT + ((size_t)b*288 + idx)*512);
    float acc0 = 0.f, acc1 = 0.f;
    #pragma unroll 4
    for (int jg = 0; jg < 128; ++jg) {
      float4 pv = vr[jg];
      float4 a0 = *(const float4*)&sA[0][h][jg*4];
      float4 a1 = *(const float4*)&sA[1][h][jg*4];
      acc0 = fmaf(pv.x, a0.x, fmaf(pv.y, a0.y, fmaf(pv.z, a0.z, fmaf(pv.w, a0.w, acc0))));
      acc1 = fmaf(pv.x, a1.x, fmaf(pv.y, a1.y, fmaf(pv.z, a1.z, fmaf(pv.w, a1.w, acc1))));
    }
    acc0 -= sT[0][x]; acc1 -= sT[1][x];
    sOPT[0][idx] = acc0; sOPT[1][idx] = acc1;
    feats[(size_t)(row0+0)*1536 + 128 + x*96 + h*12 + (r2/3)] = acc0;
    feats[(size_t)(row0+1)*1536 + 128 + x*96 + h*12 + (r2/3)] = acc1;
  }
  __syncthreads();

  // ---- o_pt norms ----
  if (tid < 192) {
    int r = tid / 96, p = tid % 96;
    float xx = sOPT[r][p*3], yy = sOPT[r][p*3+1], zz = sOPT[r][p*3+2];
    feats[(size_t)(row0+r)*1536 + 416 + p] = sqrtf(xx*xx + yy*yy + zz*zz + F_EPS);
  }

  // ---- o_pair: wave w owns j in [w*64,(w+1)*64); lane-split by row ----
  {
    const int w = tid >> 6, l = tid & 63;
    const int r = l >> 5, z4 = l & 31;
    const int jbase = w * 64;
    const float4* prp = (const float4*)(pair + (size_t)(row0 + r) * NN * DCZ);
    float4 acc[NH];
    #pragma unroll
    for (int h = 0; h < NH; ++h) acc[h] = make_float4(0.f,0.f,0.f,0.f);
    #pragma unroll 2
    for (int it = 0; it < 64; ++it) {
      const int j = jbase + it;
      float4 p = prp[(size_t)j*32 + z4];
      #pragma unroll
      for (int h = 0; h < NH; ++h) {
        float a = sA[r][h][j];
        acc[h].x = fmaf(a, p.x, acc[h].x);
        acc[h].y = fmaf(a, p.y, acc[h].y);
        acc[h].z = fmaf(a, p.z, acc[h].z);
        acc[h].w = fmaf(a, p.w, acc[h].w);
      }
    }
    #pragma unroll
    for (int h = 0; h < NH; ++h) {
      float* dst = &sOP[r][h*DCZ + z4*4];
      atomicAdd(dst+0, acc[h].x);
      atomicAdd(dst+1, acc[h].y);
      atomicAdd(dst+2, acc[h].z);
      atomicAdd(dst+3, acc[h].w);
    }
  }
  __syncthreads();
  {
    const float* sOPf = &sOP[0][0];
    for (int idx = tid; idx < 2048; idx += 512) {
      int r = idx >> 10, z = idx & 1023;
      feats[(size_t)(row0+r)*1536 + 512 + z] = sOPf[idx];
    }
  }
}

// ---------------------------------------------------------------------------
// Kernel 3: out = (seqs + feats @ Wout + bout) * mask
// 4 rows/block, 512 threads = 128 col-quads x 4 K-splits, LDS reduce.
// ---------------------------------------------------------------------------
__global__ __launch_bounds__(512) void k_out(
    const float* __restrict__ Wout, const float* __restrict__ bout,
    const float* __restrict__ seqs, const float* __restrict__ mask,
    const float* __restrict__ ws, float* __restrict__ out)
{
  const int r0 = blockIdx.x * 4;
  const int tid = threadIdx.x;
  const float* feats = ws + OFF_FT;

  __shared__ float s[4][1536];         // 24 KB
  __shared__ float pb[3][4][4][128];   // 24 KB: g, r, u, qd
  {
    float4* s4 = (float4*)s;
    const float4* f4 = (const float4*)(feats + (size_t)r0*1536);
    for (int idx = tid; idx < 1536; idx += 512) s4[idx] = f4[idx];
  }
  __syncthreads();

  const int qd = tid & 127, kh = tid >> 7;
  const int c = qd*4;
  float4 acc[4];
  #pragma unroll
  for (int r = 0; r < 4; ++r) acc[r] = make_float4(0.f,0.f,0.f,0.f);

  const int kb = kh*384;
  const float* Wp = Wout + c;
  for (int k = kb; k < kb + 384; k += 4) {
    float4 w0 = *(const float4*)(Wp + (size_t)(k+0)*512);
    float4 w1 = *(const float4*)(Wp + (size_t)(k+1)*512);
    float4 w2 = *(const float4*)(Wp + (size_t)(k+2)*512);
    float4 w3 = *(const float4*)(Wp + (size_t)(k+3)*512);
    #pragma unroll
    for (int r = 0; r < 4; ++r) {
      float4 sv = *(const float4*)&s[r][k];
      acc[r].x = fmaf(sv.x,w0.x, fmaf(sv.y,w1.x, fmaf(sv.z,w2.x, fmaf(sv.w,w3.x, acc[r].x))));
      acc[r].y = fmaf(sv.x,w0.y, fmaf(sv.y,w1.y, fmaf(sv.z,w2.y, fmaf(sv.w,w3.y, acc[r].y))));
      acc[r].z = fmaf(sv.x,w0.z, fmaf(sv.y,w1.z, fmaf(sv.z,w2.z, fmaf(sv.w,w3.z, acc[r].z))));
      acc[r].w = fmaf(sv.x,w0.w, fmaf(sv.y,w1.w, fmaf(sv.z,w2.w, fmaf(sv.w,w3.w, acc[r].w))));
    }
  }

  if (kh > 0) {
    #pragma unroll
    for (int r = 0; r < 4; ++r) {
      pb[kh-1][r][0][qd] = acc[r].x;
      pb[kh-1][r][1][qd] = acc[r].y;
      pb[kh-1][r][2][qd] = acc[r].z;
      pb[kh-1][r][3][qd] = acc[r].w;
    }
  }
  __syncthreads();
  if (kh == 0) {
    #pragma unroll
    for (int g = 0; g < 3; ++g) {
      #pragma unroll
      for (int r = 0; r < 4; ++r) {
        acc[r].x += pb[g][r][0][qd];
        acc[r].y += pb[g][r][1][qd];
        acc[r].z += pb[g][r][2][qd];
        acc[r].w += pb[g][r][3][qd];
      }
    }
    float4 bv = *(const float4*)(bout + c);
    #pragma unroll
    for (int r = 0; r < 4; ++r) {
      const int row = r0 + r;
      const float m = mask[row];
      float4 sq = *(const float4*)(seqs + (size_t)row*512 + c);
      float4 o;
      o.x = (sq.x + bv.x + acc[r].x) * m;
      o.y = (sq.y + bv.y + acc[r].y) * m;
      o.z = (sq.z + bv.z + acc[r].z) * m;
      o.w = (sq.w + bv.w + acc[r].w) * m;
      *(float4*)(out + (size_t)row*512 + c) = o;
    }
  }
}

// ---------------------------------------------------------------------------
extern "C" void kernel_launch(void* const* d_in, const int* in_sizes, int n_in,
                              void* d_out, int out_size, void* d_ws, size_t ws_size,
                              hipStream_t stream)
{
  const float* seqs   = (const float*)d_in[0];
  const float* pair   = (const float*)d_in[1];
  const float* x_t    = (const float*)d_in[2];
  const float* mask   = (const float*)d_in[3];
  const float* Wq     = (const float*)d_in[4];
  const float* bq     = (const float*)d_in[5];
  const float* Wkv    = (const float*)d_in[6];
  const float* bkv    = (const float*)d_in[7];
  const float* Wqp    = (const float*)d_in[8];
  const float* bqp    = (const float*)d_in[9];
  const float* Wkvp   = (const float*)d_in[10];
  const float* bkvp   = (const float*)d_in[11];
  const float* Wb     = (const float*)d_in[12];
  const float* bb     = (const float*)d_in[13];
  const float* head_w = (const float*)d_in[14];
  const float* Wout   = (const float*)d_in[15];
  const float* bout   = (const float*)d_in[16];
  float* out = (float*)d_out;
  float* ws  = (float*)d_ws;

  hipLaunchKernelGGL(k_proj, dim3(NB*NN/2), dim3(528), 0, stream,
                     seqs, x_t, mask, Wq, bq, Wkv, bkv, Wqp, bqp, Wkvp, bkvp, ws);
  hipLaunchKernelGGL(k_attn, dim3(NB*NN/2), dim3(512), 0, stream,
                     pair, x_t, mask, head_w, Wb, bb, ws);
  hipLaunchKernelGGL(k_out, dim3(NB*NN/4), dim3(512), 0, stream,
                     Wout, bout, seqs, mask, ws, out);
}